// Round 2
// baseline (671.320 us; speedup 1.0000x reference)
//
#include <hip/hip_runtime.h>
#include <hip/hip_bf16.h>

#define T_ 4
#define N_ 20000
#define E_ 320000
#define R_ 2
#define DIN 64
#define G_ 256   // H*Dh
#define P_ 8     // T*R
#define BPAD 18432  // 256 * 72 padded B-table halves per 64-k chunk
#define NB_ 32      // CSR-build blocks per p
#define EPB_ 10000  // edges per CSR-build block
#define CHN_ 625    // nodes per scan chunk (N_/32)

typedef unsigned short u16;
typedef __attribute__((ext_vector_type(8))) short bf16x8;
typedef __attribute__((ext_vector_type(8))) _Float16 f16x8;
typedef __attribute__((ext_vector_type(4))) float f32x4;

__device__ __forceinline__ float bf2f(u16 u) {
    unsigned int i = ((unsigned int)u) << 16; float f;
    __builtin_memcpy(&f, &i, 4); return f;
}
__device__ __forceinline__ u16 f2bf(float f) {
    unsigned int i; __builtin_memcpy(&i, &f, 4);
    unsigned int r = i + 0x7fffu + ((i >> 16) & 1u);
    return (u16)(r >> 16);
}
__device__ __forceinline__ u16 f2h(float f) {
    union { _Float16 h; u16 u; } c; c.h = (_Float16)f; return c.u;
}
__device__ __forceinline__ float sigm(float x) { return 1.f / (1.f + __expf(-x)); }
// fast tanh: 1 - 2/(exp(2x)+1); hardware v_exp_f32, correct saturation at +-inf
__device__ __forceinline__ float ftanh(float x) { return 1.f - 2.f / (__expf(2.f * x) + 1.f); }

// ds_read_b64_tr_b16: per 16-lane group, lanes at subbase + (l&15)*8B receive
// column (l&15) of the 4x16 u16 row-major tile at subbase (elem j = row j).
#define TRRD(dst, addr, off) \
    asm volatile("ds_read_b64_tr_b16 %0, %1 offset:" #off : "=v"(dst) : "v"(addr) : "memory")

// ---------------- LDS-free MFMA GEMM core (bf16 A) ----------------
__device__ __forceinline__ void gemm_direct(
    const u16* __restrict__ A, const u16* __restrict__ Bpad,
    int M, int Astride, int kchunks, int m0, f32x4* acc)
{
    const int tid = threadIdx.x;
    const int lane = tid & 63, wv = tid >> 6;
    const int col = lane & 15, quad = lane >> 4;
    #pragma unroll
    for (int cf = 0; cf < 16; ++cf) { acc[cf][0]=0.f; acc[cf][1]=0.f; acc[cf][2]=0.f; acc[cf][3]=0.f; }

    int row = m0 + wv * 16 + col;
    int row_c = (row < M) ? row : (M - 1);

    for (int kc = 0; kc < kchunks; ++kc) {
        #pragma unroll
        for (int ks = 0; ks < 2; ++ks) {
            bf16x8 a = *(const bf16x8*)(A + (size_t)row_c * Astride + kc * 64 + ks * 32 + quad * 8);
            const u16* bb = Bpad + kc * BPAD + ks * 32 + quad * 8;
            #pragma unroll
            for (int cf = 0; cf < 16; ++cf) {
                bf16x8 b = *(const bf16x8*)(bb + (cf * 16 + col) * 72);
                acc[cf] = __builtin_amdgcn_mfma_f32_16x16x32_bf16(a, b, acc[cf], 0, 0, 0);
            }
        }
    }
}

// ---------------- fold: als/ald GEMVs + x->f16 cast; wdall staged in LDS ----------------
__global__ __launch_bounds__(256) void k_fold(
    const float* __restrict__ x, const float* __restrict__ wdall,
    float* __restrict__ als_all, float* __restrict__ ald_all, u16* __restrict__ x_h)
{
    __shared__ float wds[1024];
    {
        int tid = threadIdx.x;
        *(float4*)(wds + tid * 4) = *(const float4*)(wdall + tid * 4);
    }
    __syncthreads();

    int t = blockIdx.y;
    int idx = blockIdx.x * 256 + threadIdx.x;
    if (idx >= N_ * 4) return;
    int n = idx >> 2, q = idx & 3;
    const float* xr = x + ((size_t)t * N_ + n) * 64 + q * 16;
    float4 xv[4];
    #pragma unroll
    for (int i = 0; i < 4; ++i) xv[i] = *(const float4*)(xr + i * 4);

    {
        union { u16 h[16]; ushort4 s4[4]; } cv;
        #pragma unroll
        for (int i = 0; i < 4; ++i) {
            cv.h[i*4+0] = f2h(xv[i].x); cv.h[i*4+1] = f2h(xv[i].y);
            cv.h[i*4+2] = f2h(xv[i].z); cv.h[i*4+3] = f2h(xv[i].w);
        }
        u16* xo = x_h + ((size_t)t * N_ + n) * 64 + q * 16;
        #pragma unroll
        for (int i = 0; i < 4; ++i) *(ushort4*)(xo + i * 4) = cv.s4[i];
    }

    float s[16];
    #pragma unroll
    for (int i = 0; i < 16; ++i) s[i] = 0.f;
    #pragma unroll
    for (int i = 0; i < 4; ++i) {
        float xe[4] = {xv[i].x, xv[i].y, xv[i].z, xv[i].w};
        #pragma unroll
        for (int e = 0; e < 4; ++e) {
            int k = q * 16 + i * 4 + e;
            float xk = xe[e];
            #pragma unroll
            for (int tb = 0; tb < 4; ++tb) {
                float4 w = *(const float4*)(wds + tb * 256 + k * 4);
                s[tb*4+0] += xk * w.x; s[tb*4+1] += xk * w.y;
                s[tb*4+2] += xk * w.z; s[tb*4+3] += xk * w.w;
            }
        }
    }
    #pragma unroll
    for (int i = 0; i < 16; ++i) {
        s[i] += __shfl_xor(s[i], 1);
        s[i] += __shfl_xor(s[i], 2);
    }
    if (q == 0) {
        *(float4*)(als_all + ((size_t)(t*2+0) * N_ + n) * 4) = make_float4(s[0], s[1], s[2], s[3]);
        *(float4*)(als_all + ((size_t)(t*2+1) * N_ + n) * 4) = make_float4(s[4], s[5], s[6], s[7]);
        *(float4*)(ald_all + ((size_t)(t*2+0) * N_ + n) * 4) = make_float4(s[8], s[9], s[10], s[11]);
        *(float4*)(ald_all + ((size_t)(t*2+1) * N_ + n) * 4) = make_float4(s[12], s[13], s[14], s[15]);
    }
}

// ---------------- prep: folded GEMV tables, padded B-tables, folded bias ----------------
__global__ void k_prep(const float* __restrict__ Wdst, const float* __restrict__ att_dst,
                       const float* __restrict__ Wih, const float* __restrict__ Whh,
                       const float* __restrict__ bih, const float* __restrict__ bhh,
                       const float* __restrict__ Wsrc, const float* __restrict__ att_src,
                       const float* __restrict__ raW1,
                       const float* __restrict__ Wq, const float* __restrict__ Wk,
                       const float* __restrict__ Wv,
                       float* __restrict__ wdall, float* __restrict__ biasv,
                       u16* __restrict__ raW1_pad, u16* __restrict__ Wc_pad,
                       u16* __restrict__ qkv_pad, u16* __restrict__ postB_pad)
{
    int tid = threadIdx.x, bid = blockIdx.x;
    if (bid == 0) {
        int k = tid >> 2, h = tid & 3;
        for (int r = 0; r < 2; ++r) {
            float ss = 0.f, sd = 0.f;
            for (int c = 0; c < 64; ++c) {
                ss += Wsrc[((size_t)r * 64 + k) * 256 + h * 64 + c] * att_src[r * 256 + h * 64 + c];
                sd += Wdst[((size_t)r * 64 + k) * 256 + h * 64 + c] * att_dst[r * 256 + h * 64 + c];
            }
            wdall[r * 256 + k * 4 + h] = ss;
            wdall[512 + r * 256 + k * 4 + h] = sd;
        }
        biasv[tid] = bih[tid] + bhh[tid];
    }
    for (int i = bid * 256 + tid; i < BPAD; i += gridDim.x * 256) {
        int n = i / 72, kk = i % 72;
        raW1_pad[i] = (kk < 64) ? f2bf(raW1[kk * 256 + n]) : (u16)0;
    }
    for (int i = bid * 256 + tid; i < 2 * BPAD; i += gridDim.x * 256) {
        int kc = i / BPAD, q = i % BPAD, n = q / 72, kk = q % 72;
        const float* W = kc ? Whh : Wih;
        Wc_pad[i] = (kk < 64) ? f2bf(W[n * 64 + kk]) : (u16)0;
    }
    for (int i = bid * 256 + tid; i < 192 * 72; i += gridDim.x * 256) {
        int g = i / 72, kk = i % 72;
        int j = g >> 6, c = g & 63;
        const float* W = (j == 0) ? Wq : (j == 1) ? Wk : Wv;
        qkv_pad[i] = (kk < 64) ? f2bf(W[kk * 64 + c]) : (u16)0;
    }
    for (int i = bid * 256 + tid; i < 2 * 4 * 4608; i += gridDim.x * 256) {
        int r = i / 18432, q = i % 18432, kc = q / 4608, qq = q % 4608;
        int c = qq / 72, kk = qq % 72;
        postB_pad[i] = (kk < 64) ? f2bf(Wsrc[(size_t)r * 16384 + kk * 256 + kc * 64 + c]) : (u16)0;
    }
}

// ---------------- CSR build ----------------
__global__ __launch_bounds__(256) void k_hist(const int* __restrict__ ei,
                                              u16* __restrict__ rank, u16* __restrict__ partial)
{
    __shared__ unsigned int hist[N_ / 2];
    int b = blockIdx.x, p = blockIdx.y, tid = threadIdx.x;
    for (int i = tid; i < N_ / 2; i += 256) hist[i] = 0u;
    __syncthreads();
    const int* dsts = ei + ((size_t)p * 2 + 1) * E_ + b * EPB_;
    u16* rk = rank + (size_t)p * E_ + b * EPB_;
    for (int e = tid; e < EPB_; e += 256) {
        int dst = dsts[e];
        unsigned sh = (unsigned)(dst & 1) * 16u;
        unsigned old = atomicAdd(&hist[dst >> 1], 1u << sh);
        rk[e] = (u16)((old >> sh) & 0xffffu);
    }
    __syncthreads();
    u16* part = partial + ((size_t)p * NB_ + b) * N_;
    for (int n = tid; n < N_; n += 256) {
        unsigned hv = hist[n >> 1];
        part[n] = (u16)((hv >> ((unsigned)(n & 1) * 16u)) & 0xffffu);
    }
}

__global__ __launch_bounds__(256) void k_scan1(u16* __restrict__ partial,
                                               int* __restrict__ offsets, int* __restrict__ chunktot)
{
    int p = blockIdx.y, ch = blockIdx.x;
    int tid = threadIdx.x, lane = tid & 63, wid = tid >> 6;
    __shared__ int wtot[4];
    u16* part = partial + (size_t)p * NB_ * N_;
    int* ofs = offsets + (size_t)p * (N_ + 1);
    int n0 = ch * CHN_;
    int carry = 0;
    for (int rnd = 0; rnd < 3; ++rnd) {
        int i = rnd * 256 + tid;
        int n = n0 + i;
        int v = 0;
        if (i < CHN_) {
            int run = 0;
            #pragma unroll 8
            for (int b = 0; b < NB_; ++b) {
                int pv = part[b * N_ + n];
                part[b * N_ + n] = (u16)run;
                run += pv;
            }
            v = run;
        }
        int incl = v;
        for (int d = 1; d < 64; d <<= 1) { int u = __shfl_up(incl, d); if (lane >= d) incl += u; }
        if (lane == 63) wtot[wid] = incl;
        __syncthreads();
        if (tid < 4) {
            int iv = wtot[tid];
            for (int d = 1; d < 4; d <<= 1) { int u = __shfl_up(iv, d); if (tid >= d) iv += u; }
            wtot[tid] = iv;
        }
        __syncthreads();
        int woff = (wid > 0) ? wtot[wid - 1] : 0;
        int tot = wtot[3];
        int excl = carry + woff + incl - v;
        if (i < CHN_) ofs[n] = excl;
        carry += tot;
        __syncthreads();
    }
    if (tid == 0) chunktot[p * NB_ + ch] = carry;
}

__global__ void k_scan2(const int* __restrict__ chunktot, int* __restrict__ chunkbase) {
    int tid = threadIdx.x;
    if (tid < P_) {
        int run = 0;
        for (int c = 0; c < NB_; ++c) {
            chunkbase[tid * NB_ + c] = run;
            run += chunktot[tid * NB_ + c];
        }
    }
}

__global__ void k_scan3(int* __restrict__ offsets, const int* __restrict__ chunkbase) {
    int p = blockIdx.y;
    int n = blockIdx.x * 256 + threadIdx.x;
    if (n < N_)
        offsets[(size_t)p * (N_ + 1) + n] += chunkbase[p * NB_ + n / CHN_];
    if (n == 0)
        offsets[(size_t)p * (N_ + 1) + N_] = E_;
}

__global__ void k_scatter(const int* __restrict__ ei, const int* __restrict__ offsets,
                          const u16* __restrict__ rank, const u16* __restrict__ partial,
                          u16* __restrict__ csr) {
    int p = blockIdx.y;
    int e = blockIdx.x * 256 + threadIdx.x;
    if (e >= E_) return;
    int src = ei[((size_t)p * 2 + 0) * E_ + e];
    int dst = ei[((size_t)p * 2 + 1) * E_ + e];
    int b = e / EPB_;
    int pos = offsets[p * (N_ + 1) + dst]
            + (int)partial[((size_t)p * NB_ + b) * N_ + dst]
            + (int)rank[(size_t)p * E_ + e];
    csr[(size_t)p * E_ + pos] = (u16)src;
}

// ---------------- GAT aggregation: MFMA over edge chunks ----------------
// Wave = 4 nodes. D[16 rows = 4 nodes x 4 heads][64 cols] accumulated by
// 4x mfma_f32_16x16x32_f16 per 32-edge-slot chunk (k = eo*4 + g interleave).
// A = block-diagonal p-weights (f16, built in-register from LDS p-table).
// B = gathered x rows (f16): dwordx4 gather -> 4x16-subtiled wave-private
// LDS tile -> ds_read_b64_tr_b16 fragments. Register-prefetch of next chunk.
__global__ __launch_bounds__(256) void k_agg(
    const int* __restrict__ offsets, const u16* __restrict__ csr,
    const float* __restrict__ als_all, const float* __restrict__ ald_all,
    const u16* __restrict__ x_h, u16* __restrict__ xagg4)
{
    __shared__ __align__(16) u16 xstage[4][2048];   // per-wave 32k x 64c, 4x16 subtiles
    __shared__ __align__(16) u16 ptab[4][2][256];   // [wv][rb][g*64 + h*16 + e]
    __shared__ __align__(16) int sl[4][2][64];      // [wv][rb][(e>>3)*32 + (e&7)*4 + g]
    __shared__ __align__(16) float denl[4][16];

    const int t = blockIdx.z, r_ = blockIdx.y;
    const int p = t * 2 + r_;
    const int* off   = offsets + (size_t)p * (N_ + 1);
    const u16* srcs  = csr + (size_t)p * E_;
    const float* als = als_all + (size_t)p * N_ * 4;
    const float* ald = ald_all + (size_t)p * N_ * 4;
    const u16* xb    = x_h + (size_t)t * N_ * 64;

    const int tid = threadIdx.x, lane = tid & 63, wv = tid >> 6;
    const int n0 = blockIdx.x * 16 + wv * 4;
    const int g = lane & 3, el = lane >> 2;        // p-phase mapping
    const int quad = lane >> 4, bc = lane & 15;    // MFMA mapping
    const int gw = (lane >> 2) & 3, h_ = lane & 3; // A-frag row: gw*4 + h_

    int o0 = off[n0 + g], o1 = off[n0 + g + 1];
    int deg = o1 - o0;
    int md = deg;
    md = max(md, __shfl_xor(md, 1)); md = max(md, __shfl_xor(md, 2));
    const int nchunks = (md + 7) >> 3, nrounds = (md + 15) >> 4;
    const float4 aldv = *(const float4*)(ald + (size_t)(n0 + g) * 4);
    const unsigned xsbase = (unsigned)(size_t)&xstage[wv][0];

    float den0 = 0.f, den1 = 0.f, den2 = 0.f, den3 = 0.f;
    f32x4 acc[4];
    #pragma unroll
    for (int cf = 0; cf < 4; ++cf) { acc[cf][0]=0.f; acc[cf][1]=0.f; acc[cf][2]=0.f; acc[cf][3]=0.f; }

    auto do_round = [&](int rr) {
        int e = rr * 16 + el;
        bool valid = e < deg;
        int idx = o0 + (valid ? e : 0);
        int sv = valid ? (int)srcs[idx] : 0;
        float4 av = *(const float4*)(als + (size_t)sv * 4);
        float e0 = av.x + aldv.x, e1 = av.y + aldv.y;
        float e2 = av.z + aldv.z, e3 = av.w + aldv.w;
        e0 = (e0 > 0.f) ? e0 : 0.2f * e0;
        e1 = (e1 > 0.f) ? e1 : 0.2f * e1;
        e2 = (e2 > 0.f) ? e2 : 0.2f * e2;
        e3 = (e3 > 0.f) ? e3 : 0.2f * e3;
        float p0 = valid ? __expf(e0) : 0.f;
        float p1 = valid ? __expf(e1) : 0.f;
        float p2 = valid ? __expf(e2) : 0.f;
        float p3 = valid ? __expf(e3) : 0.f;
        den0 += p0; den1 += p1; den2 += p2; den3 += p3;
        int rb = rr & 1;
        u16* pt = &ptab[wv][rb][g * 64 + el];
        pt[0]  = f2h(p0); pt[16] = f2h(p1);
        pt[32] = f2h(p2); pt[48] = f2h(p3);
        sl[wv][rb][(el >> 3) * 32 + (el & 7) * 4 + g] = sv;
    };

    auto gather = [&](int c, uint4* ldv) {
        int rb = (c >> 1) & 1, half = (c & 1) * 32;
        #pragma unroll
        for (int ps = 0; ps < 4; ++ps) {
            int k = ps * 8 + (lane >> 3);
            int sv = sl[wv][rb][half + k];
            ldv[ps] = *(const uint4*)(xb + (size_t)sv * 64 + (lane & 7) * 8);
        }
    };

    auto stage = [&](uint4* ldv) {
        int cg = lane & 7;
        #pragma unroll
        for (int ps = 0; ps < 4; ++ps) {
            int k = ps * 8 + (lane >> 3);
            int elem = ((k >> 2) * 4 + (cg >> 1)) * 64 + (k & 3) * 16 + (cg & 1) * 8;
            *(uint4*)&xstage[wv][elem] = ldv[ps];
        }
    };

    uint4 ld[4];
    if (nrounds > 0) do_round(0);
    if (nchunks > 0) gather(0, ld);

    for (int c = 0; c < nchunks; ++c) {
        if ((c & 1) && (((c + 1) >> 1) < nrounds)) do_round((c + 1) >> 1);
        uint4 ld2[4];
        bool pf = (c + 1 < nchunks);
        if (pf) gather(c + 1, ld2);
        stage(ld);

        // ---- compute chunk c ----
        int rb = (c >> 1) & 1;
        int e0l = (c & 1) * 8 + quad * 2;
        unsigned pv = *(const unsigned*)&ptab[wv][rb][gw * 64 + h_ * 16 + e0l];
        unsigned w0 = (gw == 0) ? (pv & 0xffffu) : (gw == 1) ? (pv << 16) : 0u;
        unsigned w1 = (gw == 2) ? (pv & 0xffffu) : (gw == 3) ? (pv << 16) : 0u;
        unsigned w2 = (gw == 0) ? (pv >> 16)     : (gw == 1) ? (pv & 0xffff0000u) : 0u;
        unsigned w3 = (gw == 2) ? (pv >> 16)     : (gw == 3) ? (pv & 0xffff0000u) : 0u;
        union { unsigned u[4]; f16x8 v; } avu;
        avu.u[0] = w0; avu.u[1] = w1; avu.u[2] = w2; avu.u[3] = w3;

        unsigned trb = xsbase + (unsigned)(quad * 1024 + bc * 8);
        unsigned long long b0a, b0b, b1a, b1b, b2a, b2b, b3a, b3b;
        __builtin_amdgcn_sched_barrier(0);
        TRRD(b0a, trb, 0);   TRRD(b0b, trb, 512);
        TRRD(b1a, trb, 128); TRRD(b1b, trb, 640);
        TRRD(b2a, trb, 256); TRRD(b2b, trb, 768);
        TRRD(b3a, trb, 384); TRRD(b3b, trb, 896);
        asm volatile("s_waitcnt lgkmcnt(0)" ::: "memory");
        __builtin_amdgcn_sched_barrier(0);
        union { unsigned long long q[2]; f16x8 v; } bvu;
        bvu.q[0] = b0a; bvu.q[1] = b0b;
        acc[0] = __builtin_amdgcn_mfma_f32_16x16x32_f16(avu.v, bvu.v, acc[0], 0, 0, 0);
        bvu.q[0] = b1a; bvu.q[1] = b1b;
        acc[1] = __builtin_amdgcn_mfma_f32_16x16x32_f16(avu.v, bvu.v, acc[1], 0, 0, 0);
        bvu.q[0] = b2a; bvu.q[1] = b2b;
        acc[2] = __builtin_amdgcn_mfma_f32_16x16x32_f16(avu.v, bvu.v, acc[2], 0, 0, 0);
        bvu.q[0] = b3a; bvu.q[1] = b3b;
        acc[3] = __builtin_amdgcn_mfma_f32_16x16x32_f16(avu.v, bvu.v, acc[3], 0, 0, 0);

        #pragma unroll
        for (int i = 0; i < 4; ++i) ld[i] = ld2[i];
    }

    // den reduce over el (lane bits 2..5), g preserved
    den0 += __shfl_xor(den0, 4); den0 += __shfl_xor(den0, 8);
    den0 += __shfl_xor(den0, 16); den0 += __shfl_xor(den0, 32);
    den1 += __shfl_xor(den1, 4); den1 += __shfl_xor(den1, 8);
    den1 += __shfl_xor(den1, 16); den1 += __shfl_xor(den1, 32);
    den2 += __shfl_xor(den2, 4); den2 += __shfl_xor(den2, 8);
    den2 += __shfl_xor(den2, 16); den2 += __shfl_xor(den2, 32);
    den3 += __shfl_xor(den3, 4); den3 += __shfl_xor(den3, 8);
    den3 += __shfl_xor(den3, 16); den3 += __shfl_xor(den3, 32);
    if (el == 0)
        *(float4*)&denl[wv][g * 4] = make_float4(den0, den1, den2, den3);
    float4 dv = *(const float4*)&denl[wv][quad * 4];  // den(g=quad, h=0..3), same-wave in-order DS
    float s0 = 0.25f / (dv.x + 1e-16f), s1 = 0.25f / (dv.y + 1e-16f);
    float s2 = 0.25f / (dv.z + 1e-16f), s3 = 0.25f / (dv.w + 1e-16f);

    u16* outp = xagg4 + ((size_t)p * N_ + n0 + quad) * 256 + bc;
    #pragma unroll
    for (int cf = 0; cf < 4; ++cf) {
        outp[0 * 64 + cf * 16] = f2bf(acc[cf][0] * s0);
        outp[1 * 64 + cf * 16] = f2bf(acc[cf][1] * s1);
        outp[2 * 64 + cf * 16] = f2bf(acc[cf][2] * s2);
        outp[3 * 64 + cf * 16] = f2bf(acc[cf][3] * s3);
    }
}

// ---------------- post-projection: intra = xagg @ B~ (all t in one dispatch) ----------------
__global__ __launch_bounds__(256) void k_post(
    const u16* __restrict__ xagg4, const u16* __restrict__ postB_pad,
    u16* __restrict__ intra)
{
    const int t = blockIdx.z, r = blockIdx.y;
    const u16* A = xagg4 + ((size_t)(t * 2 + r)) * N_ * 256;
    const u16* Bp = postB_pad + (size_t)r * 4 * 4608;
    const int tid = threadIdx.x, lane = tid & 63, wv = tid >> 6;
    const int col = lane & 15, quad = lane >> 4;
    int m0 = blockIdx.x * 64;
    int row = m0 + wv * 16 + col;
    int row_c = (row < N_) ? row : (N_ - 1);

    f32x4 acc[4];
    #pragma unroll
    for (int cf = 0; cf < 4; ++cf) { acc[cf][0]=0.f; acc[cf][1]=0.f; acc[cf][2]=0.f; acc[cf][3]=0.f; }
    #pragma unroll
    for (int kc = 0; kc < 4; ++kc) {
        #pragma unroll
        for (int ks = 0; ks < 2; ++ks) {
            bf16x8 a = *(const bf16x8*)(A + (size_t)row_c * 256 + kc * 64 + ks * 32 + quad * 8);
            const u16* bb = Bp + kc * 4608 + ks * 32 + quad * 8;
            #pragma unroll
            for (int cf = 0; cf < 4; ++cf) {
                bf16x8 b = *(const bf16x8*)(bb + (cf * 16 + col) * 72);
                acc[cf] = __builtin_amdgcn_mfma_f32_16x16x32_bf16(a, b, acc[cf], 0, 0, 0);
            }
        }
    }
    int rowbase = m0 + wv * 16 + quad * 4;
    #pragma unroll
    for (int cf = 0; cf < 4; ++cf) {
        int c = cf * 16 + col;
        #pragma unroll
        for (int reg = 0; reg < 4; ++reg) {
            int rr = rowbase + reg;
            if (rr < N_)
                intra[(((size_t)t * N_ + rr) * 2 + r) * 64 + c] = f2bf(acc[cf][reg]);
        }
    }
}

// ---------------- RelationAgg GEMM with fused ftanh(.)@W2 epilogue + fused beta sums ----------------
__global__ __launch_bounds__(256) void k_relagg(
    const u16* __restrict__ A, const u16* __restrict__ W1pad, const float* __restrict__ b1,
    const float* __restrict__ W2, float* __restrict__ ssum)
{
    int m0 = blockIdx.x * 64;
    f32x4 acc[16];
    gemm_direct(A, W1pad, T_ * N_ * R_, 64, 1, m0, acc);

    const int tid = threadIdx.x, lane = tid & 63, wv = tid >> 6;
    const int col = lane & 15;
    float sp[4] = {0.f, 0.f, 0.f, 0.f};
    #pragma unroll
    for (int cf = 0; cf < 16; ++cf) {
        int gcol = cf * 16 + col;
        float bb = b1[gcol];
        float ww = W2[gcol];
        #pragma unroll
        for (int reg = 0; reg < 4; ++reg)
            sp[reg] += ftanh(acc[cf][reg] + bb) * ww;
    }
    #pragma unroll
    for (int reg = 0; reg < 4; ++reg) {
        float v = sp[reg];
        v += __shfl_xor(v, 1); v += __shfl_xor(v, 2);
        v += __shfl_xor(v, 4); v += __shfl_xor(v, 8);
        sp[reg] = v;
    }
    // rows = m0 + wv*16 + quad*4 + reg ; rowbase is even so reg parity == r
    float se = sp[0] + sp[2];   // r = 0 rows of this lane's quad
    float so = sp[1] + sp[3];   // r = 1 rows
    se += __shfl_xor(se, 16); se += __shfl_xor(se, 32);
    so += __shfl_xor(so, 16); so += __shfl_xor(so, 32);
    __shared__ float red[8];
    if (lane == 0) { red[wv * 2] = se; red[wv * 2 + 1] = so; }
    __syncthreads();
    if (tid == 0) {
        float s0 = red[0] + red[2] + red[4] + red[6];
        float s1 = red[1] + red[3] + red[5] + red[7];
        int t = m0 / (N_ * R_);
        atomicAdd(&ssum[t * 2 + 0], s0);
        atomicAdd(&ssum[t * 2 + 1], s1);
    }
}

// ---------------- LSTM: all 4 timesteps in one kernel; c in regs, h in LDS ----------------
__global__ __launch_bounds__(256) void k_lstm(
    const u16* __restrict__ intra, const float* __restrict__ ssum,
    const u16* __restrict__ Wc_pad, const float* __restrict__ biasv,
    u16* __restrict__ feats)
{
    __shared__ __align__(16) u16 hl[64][72];   // h state, bf16, wave-private 16-row stripes
    const int tid = threadIdx.x, lane = tid & 63, wv = tid >> 6;
    const int col = lane & 15, quad = lane >> 4;
    int m0 = blockIdx.x * 64;
    int row = m0 + wv * 16 + col;
    int row_c = (row < N_) ? row : (N_ - 1);
    int rowbase = m0 + wv * 16 + quad * 4;

    float betas[8];
    #pragma unroll
    for (int t = 0; t < 4; ++t) {
        float s0 = ssum[t * 2] * (1.f / N_), s1 = ssum[t * 2 + 1] * (1.f / N_);
        float mx = fmaxf(s0, s1);
        float e0 = __expf(s0 - mx), e1 = __expf(s1 - mx);
        float inv = 1.f / (e0 + e1);
        betas[t * 2] = e0 * inv; betas[t * 2 + 1] = e1 * inv;
    }

    float cc[4][4];
    #pragma unroll
    for (int j = 0; j < 4; ++j)
        #pragma unroll
        for (int reg = 0; reg < 4; ++reg) cc[j][reg] = 0.f;

    for (int t = 0; t < 4; ++t) {
        float b0 = betas[t * 2], b1 = betas[t * 2 + 1];
        const u16* ib = intra + ((size_t)t * N_ + row_c) * 128;

        f32x4 acc[16];
        #pragma unroll
        for (int cf = 0; cf < 16; ++cf) { acc[cf][0]=0.f; acc[cf][1]=0.f; acc[cf][2]=0.f; acc[cf][3]=0.f; }

        #pragma unroll
        for (int ks = 0; ks < 2; ++ks) {
            int coff = ks * 32 + quad * 8;
            bf16x8 i0 = *(const bf16x8*)(ib + coff);
            bf16x8 i1 = *(const bf16x8*)(ib + 64 + coff);
            union { u16 h[8]; bf16x8 v; } cv;
            #pragma unroll
            for (int j = 0; j < 8; ++j)
                cv.h[j] = f2bf(b0 * bf2f((u16)i0[j]) + b1 * bf2f((u16)i1[j]));
            const u16* bb = Wc_pad + ks * 32 + quad * 8;
            #pragma unroll
            for (int cf = 0; cf < 16; ++cf) {
                bf16x8 b = *(const bf16x8*)(bb + (cf * 16 + col) * 72);
                acc[cf] = __builtin_amdgcn_mfma_f32_16x16x32_bf16(cv.v, b, acc[cf], 0, 0, 0);
            }
        }
        if (t > 0) {
            #pragma unroll
            for (int ks = 0; ks < 2; ++ks) {
                bf16x8 a = *(const bf16x8*)&hl[wv * 16 + col][ks * 32 + quad * 8];
                const u16* bb = Wc_pad + BPAD + ks * 32 + quad * 8;
                #pragma unroll
                for (int cf = 0; cf < 16; ++cf) {
                    bf16x8 b = *(const bf16x8*)(bb + (cf * 16 + col) * 72);
                    acc[cf] = __builtin_amdgcn_mfma_f32_16x16x32_bf16(a, b, acc[cf], 0, 0, 0);
                }
            }
        }

        #pragma unroll
        for (int j = 0; j < 4; ++j) {
            int c = j * 16 + col;
            float bi = biasv[c], bf_ = biasv[64 + c], bg = biasv[128 + c], bo = biasv[192 + c];
            #pragma unroll
            for (int reg = 0; reg < 4; ++reg) {
                float gi = acc[j][reg] + bi;
                float gf = acc[j + 4][reg] + bf_;
                float gg = acc[j + 8][reg] + bg;
                float go = acc[j + 12][reg] + bo;
                float c2 = sigm(gf) * cc[j][reg] + sigm(gi) * ftanh(gg);
                float hh = sigm(go) * ftanh(c2);
                cc[j][reg] = c2;
                u16 hb = f2bf(hh);
                hl[wv * 16 + quad * 4 + reg][c] = hb;
                int rr = rowbase + reg;
                if (rr < N_)
                    feats[(size_t)rr * 256 + t * 64 + c] = hb;
            }
        }
    }
}

// ---------------- temporal causal MHA: MFMA QKV + per-lane attention ----------------
__global__ __launch_bounds__(256) void k_attn(
    const u16* __restrict__ feats, const float* __restrict__ pos_emb,
    const u16* __restrict__ qkv_pad, float* __restrict__ out)
{
    __shared__ float qkv_s[64 * 200];
    const int tid = threadIdx.x, lane = tid & 63, wv = tid >> 6;
    const int col = lane & 15, quad = lane >> 4;
    int m0 = blockIdx.x * 64;
    int row = m0 + wv * 16 + col;
    int trow = row & 3;

    f32x4 acc[12];
    #pragma unroll
    for (int cf = 0; cf < 12; ++cf) { acc[cf][0]=0.f; acc[cf][1]=0.f; acc[cf][2]=0.f; acc[cf][3]=0.f; }
    #pragma unroll
    for (int ks = 0; ks < 2; ++ks) {
        int coff = ks * 32 + quad * 8;
        bf16x8 fv = *(const bf16x8*)(feats + (size_t)row * 64 + coff);
        float4 p0 = *(const float4*)(pos_emb + trow * 64 + coff);
        float4 p1 = *(const float4*)(pos_emb + trow * 64 + coff + 4);
        union { u16 h[8]; bf16x8 v; } cv;
        cv.h[0] = f2bf(bf2f((u16)fv[0]) + p0.x); cv.h[1] = f2bf(bf2f((u16)fv[1]) + p0.y);
        cv.h[2] = f2bf(bf2f((u16)fv[2]) + p0.z); cv.h[3] = f2bf(bf2f((u16)fv[3]) + p0.w);
        cv.h[4] = f2bf(bf2f((u16)fv[4]) + p1.x); cv.h[5] = f2bf(bf2f((u16)fv[5]) + p1.y);
        cv.h[6] = f2bf(bf2f((u16)fv[6]) + p1.z); cv.h[7] = f2bf(bf2f((u16)fv[7]) + p1.w);
        bf16x8 a = cv.v;
        const u16* bb = qkv_pad + ks * 32 + quad * 8;
        #pragma unroll
        for (int cf = 0; cf < 12; ++cf) {
            bf16x8 b = *(const bf16x8*)(bb + (cf * 16 + col) * 72);
            acc[cf] = __builtin_amdgcn_mfma_f32_16x16x32_bf16(a, b, acc[cf], 0, 0, 0);
        }
    }
    #pragma unroll
    for (int cf = 0; cf < 12; ++cf) {
        int g = cf * 16 + col;
        #pragma unroll
        for (int reg = 0; reg < 4; ++reg) {
            int rl = wv * 16 + quad * 4 + reg;
            qkv_s[rl * 200 + g] = acc[cf][reg];
        }
    }
    __syncthreads();

    int nl = wv * 4 + (lane >> 4);
    int sub = lane & 15;
    int h = sub >> 2, tq = sub & 3;
    const float* qrow = qkv_s + (nl * 4 + tq) * 200 + h * 16;

    float s[4];
    #pragma unroll
    for (int tk = 0; tk < 4; ++tk) {
        const float* krow = qkv_s + (nl * 4 + tk) * 200 + 64 + h * 16;
        float d = 0.f;
        #pragma unroll
        for (int j = 0; j < 16; ++j) d += qrow[j] * krow[j];
        s[tk] = (tk > tq) ? -4294967295.0f : d * 0.5f;
    }
    float mx = fmaxf(fmaxf(s[0], s[1]), fmaxf(s[2], s[3]));
    float a0 = __expf(s[0]-mx), a1 = __expf(s[1]-mx), a2 = __expf(s[2]-mx), a3 = __expf(s[3]-mx);
    float inv = 1.f / (a0 + a1 + a2 + a3);
    a0 *= inv; a1 *= inv; a2 *= inv; a3 *= inv;

    int n = blockIdx.x * 16 + nl;
    const float* v0 = qkv_s + (nl * 4 + 0) * 200 + 128 + h * 16;
    const float* v1 = v0 + 200, *v2 = v0 + 400, *v3 = v0 + 600;
    #pragma unroll
    for (int cc4 = 0; cc4 < 4; ++cc4) {
        float4 o;
        o.x = a0*v0[cc4*4+0] + a1*v1[cc4*4+0] + a2*v2[cc4*4+0] + a3*v3[cc4*4+0];
        o.y = a0*v0[cc4*4+1] + a1*v1[cc4*4+1] + a2*v2[cc4*4+1] + a3*v3[cc4*4+1];
        o.z = a0*v0[cc4*4+2] + a1*v1[cc4*4+2] + a2*v2[cc4*4+2] + a3*v3[cc4*4+2];
        o.w = a0*v0[cc4*4+3] + a1*v1[cc4*4+3] + a2*v2[cc4*4+3] + a3*v3[cc4*4+3];
        *(float4*)(out + (size_t)n * 256 + tq * 64 + h * 16 + cc4 * 4) = o;
    }
}

// ---------------- launcher ----------------
extern "C" void kernel_launch(void* const* d_in, const int* in_sizes, int n_in,
                              void* d_out, int out_size, void* d_ws, size_t ws_size,
                              hipStream_t stream) {
    const float* x     = (const float*)d_in[0];
    const int* ei      = (const int*)d_in[1];
    const float* Wsrc  = (const float*)d_in[2];
    const float* Wdst  = (const float*)d_in[3];
    const float* att_src = (const float*)d_in[4];
    const float* att_dst = (const float*)d_in[5];
    const float* raW1  = (const float*)d_in[6];
    const float* rab1  = (const float*)d_in[7];
    const float* raW2  = (const float*)d_in[8];
    const float* Wih   = (const float*)d_in[9];
    const float* Whh   = (const float*)d_in[10];
    const float* bih   = (const float*)d_in[11];
    const float* bhh   = (const float*)d_in[12];
    const float* pos   = (const float*)d_in[13];
    const float* Wq    = (const float*)d_in[14];
    const float* Wk    = (const float*)d_in[15];
    const float* Wv    = (const float*)d_in[16];
    float* out = (float*)d_out;

    char* w = (char*)d_ws;
    size_t off = 0;
    auto alloc = [&](size_t bytes) -> char* {
        char* pp = w + off; off += (bytes + 255) & ~(size_t)255; return pp;
    };
    // ---- long-lived ----
    u16*   intra     = (u16*)  alloc((size_t)T_ * N_ * R_ * 64 * 2);  // 20.48 MB
    u16*   x_h       = (u16*)  alloc((size_t)T_ * N_ * 64 * 2);       // 10.24 MB (f16)
    float* ssum      = (float*)alloc(256);
    float* wdall     = (float*)alloc(1024 * 4);
    float* biasv     = (float*)alloc(256 * 4);
    u16*   raW1_pad  = (u16*)  alloc(BPAD * 2);
    u16*   Wc_pad    = (u16*)  alloc(2 * BPAD * 2);
    u16*   qkv_pad   = (u16*)  alloc(192 * 72 * 2);
    u16*   postB_pad = (u16*)  alloc(2 * 4 * 4608 * 2);
    int*   chunktot  = (int*)  alloc(P_ * NB_ * 4);
    int*   chunkbase = (int*)  alloc(P_ * NB_ * 4);
    // ---- union region ----
    char*  ubase   = alloc(0);
    size_t uoff = 0;
    auto ualloc = [&](size_t bytes) -> char* {
        char* pp = ubase + uoff; uoff += (bytes + 255) & ~(size_t)255; return pp;
    };
    int*   offsets = (int*)  ualloc((size_t)P_ * (N_ + 1) * 4);
    u16*   csr     = (u16*)  ualloc((size_t)P_ * E_ * 2);
    float* als_all = (float*)ualloc((size_t)P_ * N_ * 4 * 4);
    float* ald_all = (float*)ualloc((size_t)P_ * N_ * 4 * 4);
    u16*   partial = (u16*)  ualloc((size_t)P_ * NB_ * N_ * 2);
    u16*   xagg4   = (u16*)  ualloc((size_t)P_ * N_ * 256 * 2);   // 81.92 MB (all t,r)
    u16*   rank    = (u16*)  xagg4;   // overlay: rank dead before k_agg
    // phase 2 overlay (phase-1 sub-buffers dead after k_post)
    u16*   feats   = (u16*)  ubase;   // 10.24 MB
    (void)ws_size; (void)in_sizes; (void)n_in; (void)out_size;

    k_prep<<<72, 256, 0, stream>>>(Wdst, att_dst, Wih, Whh, bih, bhh, Wsrc, att_src, raW1,
                                   Wq, Wk, Wv, wdall, biasv, raW1_pad, Wc_pad, qkv_pad, postB_pad);
    k_hist<<<dim3(NB_, 8), 256, 0, stream>>>(ei, rank, partial);
    k_scan1<<<dim3(NB_, 8), 256, 0, stream>>>(partial, offsets, chunktot);
    k_scan2<<<1, 64, 0, stream>>>(chunktot, chunkbase);
    k_scan3<<<dim3(79, 8), 256, 0, stream>>>(offsets, chunkbase);
    k_scatter<<<dim3(1250, 8), 256, 0, stream>>>(ei, offsets, rank, partial, csr);
    k_fold<<<dim3(313, 4), 256, 0, stream>>>(x, wdall, als_all, ald_all, x_h);
    k_agg<<<dim3(1250, 2, 4), 256, 0, stream>>>(offsets, csr, als_all, ald_all, x_h, xagg4);
    k_post<<<dim3(313, 2, 4), 256, 0, stream>>>(xagg4, postB_pad, intra);
    hipMemsetAsync(ssum, 0, 32, stream);
    k_relagg<<<2500, 256, 0, stream>>>(intra, raW1_pad, rab1, raW2, ssum);
    k_lstm<<<313, 256, 0, stream>>>(intra, ssum, Wc_pad, biasv, feats);
    k_attn<<<1250, 256, 0, stream>>>(feats, pos, qkv_pad, out);
}

// Round 3
// 483.351 us; speedup vs baseline: 1.3889x; 1.3889x over previous
//
#include <hip/hip_runtime.h>
#include <hip/hip_bf16.h>

#define T_ 4
#define N_ 20000
#define E_ 320000
#define R_ 2
#define DIN 64
#define G_ 256   // H*Dh
#define P_ 8     // T*R
#define BPAD 18432  // 256 * 72 padded B-table halves per 64-k chunk
#define NB_ 32      // CSR-build blocks per p
#define EPB_ 10000  // edges per CSR-build block
#define CHN_ 625    // nodes per scan chunk (N_/32)

typedef unsigned short u16;
typedef __attribute__((ext_vector_type(8))) short bf16x8;
typedef __attribute__((ext_vector_type(4))) float f32x4;

__device__ __forceinline__ float bf2f(u16 u) {
    unsigned int i = ((unsigned int)u) << 16; float f;
    __builtin_memcpy(&f, &i, 4); return f;
}
__device__ __forceinline__ u16 f2bf(float f) {
    unsigned int i; __builtin_memcpy(&i, &f, 4);
    unsigned int r = i + 0x7fffu + ((i >> 16) & 1u);
    return (u16)(r >> 16);
}
__device__ __forceinline__ float sigm(float x) { return 1.f / (1.f + __expf(-x)); }
// fast tanh: 1 - 2/(exp(2x)+1); hardware v_exp_f32, correct saturation at +-inf
__device__ __forceinline__ float ftanh(float x) { return 1.f - 2.f / (__expf(2.f * x) + 1.f); }

// ---------------- LDS-free MFMA GEMM core (bf16 A) ----------------
__device__ __forceinline__ void gemm_direct(
    const u16* __restrict__ A, const u16* __restrict__ Bpad,
    int M, int Astride, int kchunks, int m0, f32x4* acc)
{
    const int tid = threadIdx.x;
    const int lane = tid & 63, wv = tid >> 6;
    const int col = lane & 15, quad = lane >> 4;
    #pragma unroll
    for (int cf = 0; cf < 16; ++cf) { acc[cf][0]=0.f; acc[cf][1]=0.f; acc[cf][2]=0.f; acc[cf][3]=0.f; }

    int row = m0 + wv * 16 + col;
    int row_c = (row < M) ? row : (M - 1);

    for (int kc = 0; kc < kchunks; ++kc) {
        #pragma unroll
        for (int ks = 0; ks < 2; ++ks) {
            bf16x8 a = *(const bf16x8*)(A + (size_t)row_c * Astride + kc * 64 + ks * 32 + quad * 8);
            const u16* bb = Bpad + kc * BPAD + ks * 32 + quad * 8;
            #pragma unroll
            for (int cf = 0; cf < 16; ++cf) {
                bf16x8 b = *(const bf16x8*)(bb + (cf * 16 + col) * 72);
                acc[cf] = __builtin_amdgcn_mfma_f32_16x16x32_bf16(a, b, acc[cf], 0, 0, 0);
            }
        }
    }
}

// ---------------- fold: als/ald GEMVs + x->bf16 cast; wdall staged in LDS ----------------
__global__ __launch_bounds__(256) void k_fold(
    const float* __restrict__ x, const float* __restrict__ wdall,
    float* __restrict__ als_all, float* __restrict__ ald_all, u16* __restrict__ x_bf)
{
    __shared__ float wds[1024];
    {
        int tid = threadIdx.x;
        *(float4*)(wds + tid * 4) = *(const float4*)(wdall + tid * 4);
    }
    __syncthreads();

    int t = blockIdx.y;
    int idx = blockIdx.x * 256 + threadIdx.x;
    if (idx >= N_ * 4) return;
    int n = idx >> 2, q = idx & 3;
    const float* xr = x + ((size_t)t * N_ + n) * 64 + q * 16;
    float4 xv[4];
    #pragma unroll
    for (int i = 0; i < 4; ++i) xv[i] = *(const float4*)(xr + i * 4);

    {
        union { u16 h[16]; ushort4 s4[4]; } cv;
        #pragma unroll
        for (int i = 0; i < 4; ++i) {
            cv.h[i*4+0] = f2bf(xv[i].x); cv.h[i*4+1] = f2bf(xv[i].y);
            cv.h[i*4+2] = f2bf(xv[i].z); cv.h[i*4+3] = f2bf(xv[i].w);
        }
        u16* xo = x_bf + ((size_t)t * N_ + n) * 64 + q * 16;
        #pragma unroll
        for (int i = 0; i < 4; ++i) *(ushort4*)(xo + i * 4) = cv.s4[i];
    }

    float s[16];
    #pragma unroll
    for (int i = 0; i < 16; ++i) s[i] = 0.f;
    #pragma unroll
    for (int i = 0; i < 4; ++i) {
        float xe[4] = {xv[i].x, xv[i].y, xv[i].z, xv[i].w};
        #pragma unroll
        for (int e = 0; e < 4; ++e) {
            int k = q * 16 + i * 4 + e;
            float xk = xe[e];
            #pragma unroll
            for (int tb = 0; tb < 4; ++tb) {
                float4 w = *(const float4*)(wds + tb * 256 + k * 4);
                s[tb*4+0] += xk * w.x; s[tb*4+1] += xk * w.y;
                s[tb*4+2] += xk * w.z; s[tb*4+3] += xk * w.w;
            }
        }
    }
    #pragma unroll
    for (int i = 0; i < 16; ++i) {
        s[i] += __shfl_xor(s[i], 1);
        s[i] += __shfl_xor(s[i], 2);
    }
    if (q == 0) {
        *(float4*)(als_all + ((size_t)(t*2+0) * N_ + n) * 4) = make_float4(s[0], s[1], s[2], s[3]);
        *(float4*)(als_all + ((size_t)(t*2+1) * N_ + n) * 4) = make_float4(s[4], s[5], s[6], s[7]);
        *(float4*)(ald_all + ((size_t)(t*2+0) * N_ + n) * 4) = make_float4(s[8], s[9], s[10], s[11]);
        *(float4*)(ald_all + ((size_t)(t*2+1) * N_ + n) * 4) = make_float4(s[12], s[13], s[14], s[15]);
    }
}

// ---------------- prep: folded GEMV tables, padded B-tables, folded bias ----------------
__global__ void k_prep(const float* __restrict__ Wdst, const float* __restrict__ att_dst,
                       const float* __restrict__ Wih, const float* __restrict__ Whh,
                       const float* __restrict__ bih, const float* __restrict__ bhh,
                       const float* __restrict__ Wsrc, const float* __restrict__ att_src,
                       const float* __restrict__ raW1,
                       const float* __restrict__ Wq, const float* __restrict__ Wk,
                       const float* __restrict__ Wv,
                       float* __restrict__ wdall, float* __restrict__ biasv,
                       u16* __restrict__ raW1_pad, u16* __restrict__ Wc_pad,
                       u16* __restrict__ qkv_pad, u16* __restrict__ postB_pad)
{
    int tid = threadIdx.x, bid = blockIdx.x;
    if (bid == 0) {
        int k = tid >> 2, h = tid & 3;
        for (int r = 0; r < 2; ++r) {
            float ss = 0.f, sd = 0.f;
            for (int c = 0; c < 64; ++c) {
                ss += Wsrc[((size_t)r * 64 + k) * 256 + h * 64 + c] * att_src[r * 256 + h * 64 + c];
                sd += Wdst[((size_t)r * 64 + k) * 256 + h * 64 + c] * att_dst[r * 256 + h * 64 + c];
            }
            wdall[r * 256 + k * 4 + h] = ss;
            wdall[512 + r * 256 + k * 4 + h] = sd;
        }
        biasv[tid] = bih[tid] + bhh[tid];
    }
    for (int i = bid * 256 + tid; i < BPAD; i += gridDim.x * 256) {
        int n = i / 72, kk = i % 72;
        raW1_pad[i] = (kk < 64) ? f2bf(raW1[kk * 256 + n]) : (u16)0;
    }
    for (int i = bid * 256 + tid; i < 2 * BPAD; i += gridDim.x * 256) {
        int kc = i / BPAD, q = i % BPAD, n = q / 72, kk = q % 72;
        const float* W = kc ? Whh : Wih;
        Wc_pad[i] = (kk < 64) ? f2bf(W[n * 64 + kk]) : (u16)0;
    }
    for (int i = bid * 256 + tid; i < 192 * 72; i += gridDim.x * 256) {
        int g = i / 72, kk = i % 72;
        int j = g >> 6, c = g & 63;
        const float* W = (j == 0) ? Wq : (j == 1) ? Wk : Wv;
        qkv_pad[i] = (kk < 64) ? f2bf(W[kk * 64 + c]) : (u16)0;
    }
    for (int i = bid * 256 + tid; i < 2 * 4 * 4608; i += gridDim.x * 256) {
        int r = i / 18432, q = i % 18432, kc = q / 4608, qq = q % 4608;
        int c = qq / 72, kk = qq % 72;
        postB_pad[i] = (kk < 64) ? f2bf(Wsrc[(size_t)r * 16384 + kk * 256 + kc * 64 + c]) : (u16)0;
    }
}

// ---------------- CSR build ----------------
__global__ __launch_bounds__(256) void k_hist(const int* __restrict__ ei,
                                              u16* __restrict__ rank, u16* __restrict__ partial)
{
    __shared__ unsigned int hist[N_ / 2];
    int b = blockIdx.x, p = blockIdx.y, tid = threadIdx.x;
    for (int i = tid; i < N_ / 2; i += 256) hist[i] = 0u;
    __syncthreads();
    const int* dsts = ei + ((size_t)p * 2 + 1) * E_ + b * EPB_;
    u16* rk = rank + (size_t)p * E_ + b * EPB_;
    for (int e = tid; e < EPB_; e += 256) {
        int dst = dsts[e];
        unsigned sh = (unsigned)(dst & 1) * 16u;
        unsigned old = atomicAdd(&hist[dst >> 1], 1u << sh);
        rk[e] = (u16)((old >> sh) & 0xffffu);
    }
    __syncthreads();
    u16* part = partial + ((size_t)p * NB_ + b) * N_;
    for (int n = tid; n < N_; n += 256) {
        unsigned hv = hist[n >> 1];
        part[n] = (u16)((hv >> ((unsigned)(n & 1) * 16u)) & 0xffffu);
    }
}

__global__ __launch_bounds__(256) void k_scan1(u16* __restrict__ partial,
                                               int* __restrict__ offsets, int* __restrict__ chunktot)
{
    int p = blockIdx.y, ch = blockIdx.x;
    int tid = threadIdx.x, lane = tid & 63, wid = tid >> 6;
    __shared__ int wtot[4];
    u16* part = partial + (size_t)p * NB_ * N_;
    int* ofs = offsets + (size_t)p * (N_ + 1);
    int n0 = ch * CHN_;
    int carry = 0;
    for (int rnd = 0; rnd < 3; ++rnd) {
        int i = rnd * 256 + tid;
        int n = n0 + i;
        int v = 0;
        if (i < CHN_) {
            int run = 0;
            #pragma unroll 8
            for (int b = 0; b < NB_; ++b) {
                int pv = part[b * N_ + n];
                part[b * N_ + n] = (u16)run;
                run += pv;
            }
            v = run;
        }
        int incl = v;
        for (int d = 1; d < 64; d <<= 1) { int u = __shfl_up(incl, d); if (lane >= d) incl += u; }
        if (lane == 63) wtot[wid] = incl;
        __syncthreads();
        if (tid < 4) {
            int iv = wtot[tid];
            for (int d = 1; d < 4; d <<= 1) { int u = __shfl_up(iv, d); if (tid >= d) iv += u; }
            wtot[tid] = iv;
        }
        __syncthreads();
        int woff = (wid > 0) ? wtot[wid - 1] : 0;
        int tot = wtot[3];
        int excl = carry + woff + incl - v;
        if (i < CHN_) ofs[n] = excl;
        carry += tot;
        __syncthreads();
    }
    if (tid == 0) chunktot[p * NB_ + ch] = carry;
}

__global__ void k_scan2(const int* __restrict__ chunktot, int* __restrict__ chunkbase) {
    int tid = threadIdx.x;
    if (tid < P_) {
        int run = 0;
        for (int c = 0; c < NB_; ++c) {
            chunkbase[tid * NB_ + c] = run;
            run += chunktot[tid * NB_ + c];
        }
    }
}

__global__ void k_scan3(int* __restrict__ offsets, const int* __restrict__ chunkbase) {
    int p = blockIdx.y;
    int n = blockIdx.x * 256 + threadIdx.x;
    if (n < N_)
        offsets[(size_t)p * (N_ + 1) + n] += chunkbase[p * NB_ + n / CHN_];
    if (n == 0)
        offsets[(size_t)p * (N_ + 1) + N_] = E_;
}

__global__ void k_scatter(const int* __restrict__ ei, const int* __restrict__ offsets,
                          const u16* __restrict__ rank, const u16* __restrict__ partial,
                          u16* __restrict__ csr) {
    int p = blockIdx.y;
    int e = blockIdx.x * 256 + threadIdx.x;
    if (e >= E_) return;
    int src = ei[((size_t)p * 2 + 0) * E_ + e];
    int dst = ei[((size_t)p * 2 + 1) * E_ + e];
    int b = e / EPB_;
    int pos = offsets[p * (N_ + 1) + dst]
            + (int)partial[((size_t)p * NB_ + b) * N_ + dst]
            + (int)rank[(size_t)p * E_ + e];
    csr[(size_t)p * E_ + pos] = (u16)src;
}

// ---------------- GAT aggregation: lane-per-column, LDS p-broadcast, SGPR gather base ---------
// Lane = feature column (0..63); 4 head accumulators per lane. Per <=64-edge batch:
// p-phase (lane = edge slot) computes 4 exps/edge, stashes {src, p4} in wave-private
// LDS (in-order DS pipe within a wave -> no barrier). x-phase reads the wave-uniform
// src via readfirstlane -> SGPR base, so the gather is global_load_ushort with a
// scalar base + constant lane offset (address math on the SALU pipe, not VALU).
__global__ __launch_bounds__(256) void k_agg(
    const int* __restrict__ offsets, const u16* __restrict__ csr,
    const float* __restrict__ als_all, const float* __restrict__ ald_all,
    const u16* __restrict__ x_bf, u16* __restrict__ xagg4)
{
    __shared__ float4 pl[4][64];
    __shared__ int    sl[4][64];
    const int t = blockIdx.z, r = blockIdx.y;
    const int p = t * 2 + r;
    const int* off   = offsets + (size_t)p * (N_ + 1);
    const u16* srcs  = csr + (size_t)p * E_;
    const float* als = als_all + (size_t)p * N_ * 4;
    const float* ald = ald_all + (size_t)p * N_ * 4;
    const u16* xb    = x_bf + (size_t)t * N_ * 64;

    const int tid = threadIdx.x, lane = tid & 63, wv = tid >> 6;
    const int n = blockIdx.x * 4 + wv;
    const int o0 = off[n], o1 = off[n + 1];
    const float4 aldv = *(const float4*)(ald + (size_t)n * 4);

    float a0 = 0.f, a1 = 0.f, a2 = 0.f, a3 = 0.f;
    float d0 = 0.f, d1 = 0.f, d2 = 0.f, d3 = 0.f;

    for (int base = o0; base < o1; base += 64) {
        int cnt = o1 - base; if (cnt > 64) cnt = 64;
        int sv = 0;
        float p0 = 0.f, p1 = 0.f, p2 = 0.f, p3 = 0.f;
        if (lane < cnt) {
            sv = (int)srcs[base + lane];
            float4 av = *(const float4*)(als + (size_t)sv * 4);
            float e0 = av.x + aldv.x, e1 = av.y + aldv.y;
            float e2 = av.z + aldv.z, e3 = av.w + aldv.w;
            e0 = (e0 > 0.f) ? e0 : 0.2f * e0;
            e1 = (e1 > 0.f) ? e1 : 0.2f * e1;
            e2 = (e2 > 0.f) ? e2 : 0.2f * e2;
            e3 = (e3 > 0.f) ? e3 : 0.2f * e3;
            p0 = __expf(e0); p1 = __expf(e1); p2 = __expf(e2); p3 = __expf(e3);
        }
        d0 += p0; d1 += p1; d2 += p2; d3 += p3;
        pl[wv][lane] = make_float4(p0, p1, p2, p3);
        sl[wv][lane] = sv;
        // lanes >= cnt wrote p=0, s=0 -> padded iterations contribute zero
        int cntR = (cnt + 7) & ~7;
        for (int j0 = 0; j0 < cntR; j0 += 8) {
            u16 xv[8];
            #pragma unroll
            for (int jj = 0; jj < 8; ++jj) {
                int s = __builtin_amdgcn_readfirstlane(sl[wv][j0 + jj]);
                xv[jj] = xb[((size_t)(unsigned)s << 6) + lane];
            }
            #pragma unroll
            for (int jj = 0; jj < 8; ++jj) {
                float4 pj = pl[wv][j0 + jj];
                float f = bf2f(xv[jj]);
                a0 += pj.x * f; a1 += pj.y * f;
                a2 += pj.z * f; a3 += pj.w * f;
            }
        }
    }
    #pragma unroll
    for (int m = 1; m < 64; m <<= 1) {
        d0 += __shfl_xor(d0, m); d1 += __shfl_xor(d1, m);
        d2 += __shfl_xor(d2, m); d3 += __shfl_xor(d3, m);
    }
    float s0 = 0.25f / (d0 + 1e-16f), s1 = 0.25f / (d1 + 1e-16f);
    float s2 = 0.25f / (d2 + 1e-16f), s3 = 0.25f / (d3 + 1e-16f);
    u16* outp = xagg4 + ((size_t)p * N_ + n) * 256 + lane;
    outp[0]   = f2bf(a0 * s0);
    outp[64]  = f2bf(a1 * s1);
    outp[128] = f2bf(a2 * s2);
    outp[192] = f2bf(a3 * s3);
}

// ---------------- post-projection: intra = xagg @ B~ (all t in one dispatch) ----------------
__global__ __launch_bounds__(256) void k_post(
    const u16* __restrict__ xagg4, const u16* __restrict__ postB_pad,
    u16* __restrict__ intra)
{
    const int t = blockIdx.z, r = blockIdx.y;
    const u16* A = xagg4 + ((size_t)(t * 2 + r)) * N_ * 256;
    const u16* Bp = postB_pad + (size_t)r * 4 * 4608;
    const int tid = threadIdx.x, lane = tid & 63, wv = tid >> 6;
    const int col = lane & 15, quad = lane >> 4;
    int m0 = blockIdx.x * 64;
    int row = m0 + wv * 16 + col;
    int row_c = (row < N_) ? row : (N_ - 1);

    f32x4 acc[4];
    #pragma unroll
    for (int cf = 0; cf < 4; ++cf) { acc[cf][0]=0.f; acc[cf][1]=0.f; acc[cf][2]=0.f; acc[cf][3]=0.f; }
    #pragma unroll
    for (int kc = 0; kc < 4; ++kc) {
        #pragma unroll
        for (int ks = 0; ks < 2; ++ks) {
            bf16x8 a = *(const bf16x8*)(A + (size_t)row_c * 256 + kc * 64 + ks * 32 + quad * 8);
            const u16* bb = Bp + kc * 4608 + ks * 32 + quad * 8;
            #pragma unroll
            for (int cf = 0; cf < 4; ++cf) {
                bf16x8 b = *(const bf16x8*)(bb + (cf * 16 + col) * 72);
                acc[cf] = __builtin_amdgcn_mfma_f32_16x16x32_bf16(a, b, acc[cf], 0, 0, 0);
            }
        }
    }
    int rowbase = m0 + wv * 16 + quad * 4;
    #pragma unroll
    for (int cf = 0; cf < 4; ++cf) {
        int c = cf * 16 + col;
        #pragma unroll
        for (int reg = 0; reg < 4; ++reg) {
            int rr = rowbase + reg;
            if (rr < N_)
                intra[(((size_t)t * N_ + rr) * 2 + r) * 64 + c] = f2bf(acc[cf][reg]);
        }
    }
}

// ---------------- RelationAgg GEMM with fused ftanh(.)@W2 epilogue + fused beta sums ----------------
__global__ __launch_bounds__(256) void k_relagg(
    const u16* __restrict__ A, const u16* __restrict__ W1pad, const float* __restrict__ b1,
    const float* __restrict__ W2, float* __restrict__ ssum)
{
    int m0 = blockIdx.x * 64;
    f32x4 acc[16];
    gemm_direct(A, W1pad, T_ * N_ * R_, 64, 1, m0, acc);

    const int tid = threadIdx.x, lane = tid & 63, wv = tid >> 6;
    const int col = lane & 15;
    float sp[4] = {0.f, 0.f, 0.f, 0.f};
    #pragma unroll
    for (int cf = 0; cf < 16; ++cf) {
        int gcol = cf * 16 + col;
        float bb = b1[gcol];
        float ww = W2[gcol];
        #pragma unroll
        for (int reg = 0; reg < 4; ++reg)
            sp[reg] += ftanh(acc[cf][reg] + bb) * ww;
    }
    #pragma unroll
    for (int reg = 0; reg < 4; ++reg) {
        float v = sp[reg];
        v += __shfl_xor(v, 1); v += __shfl_xor(v, 2);
        v += __shfl_xor(v, 4); v += __shfl_xor(v, 8);
        sp[reg] = v;
    }
    // rows = m0 + wv*16 + quad*4 + reg ; rowbase is even so reg parity == r
    float se = sp[0] + sp[2];   // r = 0 rows of this lane's quad
    float so = sp[1] + sp[3];   // r = 1 rows
    se += __shfl_xor(se, 16); se += __shfl_xor(se, 32);
    so += __shfl_xor(so, 16); so += __shfl_xor(so, 32);
    __shared__ float red[8];
    if (lane == 0) { red[wv * 2] = se; red[wv * 2 + 1] = so; }
    __syncthreads();
    if (tid == 0) {
        float s0 = red[0] + red[2] + red[4] + red[6];
        float s1 = red[1] + red[3] + red[5] + red[7];
        int t = m0 / (N_ * R_);
        atomicAdd(&ssum[t * 2 + 0], s0);
        atomicAdd(&ssum[t * 2 + 1], s1);
    }
}

// ---------------- LSTM: all 4 timesteps in one kernel; c in regs, h in LDS ----------------
__global__ __launch_bounds__(256) void k_lstm(
    const u16* __restrict__ intra, const float* __restrict__ ssum,
    const u16* __restrict__ Wc_pad, const float* __restrict__ biasv,
    u16* __restrict__ feats)
{
    __shared__ __align__(16) u16 hl[64][72];   // h state, bf16, wave-private 16-row stripes
    const int tid = threadIdx.x, lane = tid & 63, wv = tid >> 6;
    const int col = lane & 15, quad = lane >> 4;
    int m0 = blockIdx.x * 64;
    int row = m0 + wv * 16 + col;
    int row_c = (row < N_) ? row : (N_ - 1);
    int rowbase = m0 + wv * 16 + quad * 4;

    float betas[8];
    #pragma unroll
    for (int t = 0; t < 4; ++t) {
        float s0 = ssum[t * 2] * (1.f / N_), s1 = ssum[t * 2 + 1] * (1.f / N_);
        float mx = fmaxf(s0, s1);
        float e0 = __expf(s0 - mx), e1 = __expf(s1 - mx);
        float inv = 1.f / (e0 + e1);
        betas[t * 2] = e0 * inv; betas[t * 2 + 1] = e1 * inv;
    }

    float cc[4][4];
    #pragma unroll
    for (int j = 0; j < 4; ++j)
        #pragma unroll
        for (int reg = 0; reg < 4; ++reg) cc[j][reg] = 0.f;

    for (int t = 0; t < 4; ++t) {
        float b0 = betas[t * 2], b1 = betas[t * 2 + 1];
        const u16* ib = intra + ((size_t)t * N_ + row_c) * 128;

        f32x4 acc[16];
        #pragma unroll
        for (int cf = 0; cf < 16; ++cf) { acc[cf][0]=0.f; acc[cf][1]=0.f; acc[cf][2]=0.f; acc[cf][3]=0.f; }

        #pragma unroll
        for (int ks = 0; ks < 2; ++ks) {
            int coff = ks * 32 + quad * 8;
            bf16x8 i0 = *(const bf16x8*)(ib + coff);
            bf16x8 i1 = *(const bf16x8*)(ib + 64 + coff);
            union { u16 h[8]; bf16x8 v; } cv;
            #pragma unroll
            for (int j = 0; j < 8; ++j)
                cv.h[j] = f2bf(b0 * bf2f((u16)i0[j]) + b1 * bf2f((u16)i1[j]));
            const u16* bb = Wc_pad + ks * 32 + quad * 8;
            #pragma unroll
            for (int cf = 0; cf < 16; ++cf) {
                bf16x8 b = *(const bf16x8*)(bb + (cf * 16 + col) * 72);
                acc[cf] = __builtin_amdgcn_mfma_f32_16x16x32_bf16(cv.v, b, acc[cf], 0, 0, 0);
            }
        }
        if (t > 0) {
            #pragma unroll
            for (int ks = 0; ks < 2; ++ks) {
                bf16x8 a = *(const bf16x8*)&hl[wv * 16 + col][ks * 32 + quad * 8];
                const u16* bb = Wc_pad + BPAD + ks * 32 + quad * 8;
                #pragma unroll
                for (int cf = 0; cf < 16; ++cf) {
                    bf16x8 b = *(const bf16x8*)(bb + (cf * 16 + col) * 72);
                    acc[cf] = __builtin_amdgcn_mfma_f32_16x16x32_bf16(a, b, acc[cf], 0, 0, 0);
                }
            }
        }

        #pragma unroll
        for (int j = 0; j < 4; ++j) {
            int c = j * 16 + col;
            float bi = biasv[c], bf_ = biasv[64 + c], bg = biasv[128 + c], bo = biasv[192 + c];
            #pragma unroll
            for (int reg = 0; reg < 4; ++reg) {
                float gi = acc[j][reg] + bi;
                float gf = acc[j + 4][reg] + bf_;
                float gg = acc[j + 8][reg] + bg;
                float go = acc[j + 12][reg] + bo;
                float c2 = sigm(gf) * cc[j][reg] + sigm(gi) * ftanh(gg);
                float hh = sigm(go) * ftanh(c2);
                cc[j][reg] = c2;
                u16 hb = f2bf(hh);
                hl[wv * 16 + quad * 4 + reg][c] = hb;
                int rr = rowbase + reg;
                if (rr < N_)
                    feats[(size_t)rr * 256 + t * 64 + c] = hb;
            }
        }
    }
}

// ---------------- temporal causal MHA: MFMA QKV + per-lane attention ----------------
__global__ __launch_bounds__(256) void k_attn(
    const u16* __restrict__ feats, const float* __restrict__ pos_emb,
    const u16* __restrict__ qkv_pad, float* __restrict__ out)
{
    __shared__ float qkv_s[64 * 200];
    const int tid = threadIdx.x, lane = tid & 63, wv = tid >> 6;
    const int col = lane & 15, quad = lane >> 4;
    int m0 = blockIdx.x * 64;
    int row = m0 + wv * 16 + col;
    int trow = row & 3;

    f32x4 acc[12];
    #pragma unroll
    for (int cf = 0; cf < 12; ++cf) { acc[cf][0]=0.f; acc[cf][1]=0.f; acc[cf][2]=0.f; acc[cf][3]=0.f; }
    #pragma unroll
    for (int ks = 0; ks < 2; ++ks) {
        int coff = ks * 32 + quad * 8;
        bf16x8 fv = *(const bf16x8*)(feats + (size_t)row * 64 + coff);
        float4 p0 = *(const float4*)(pos_emb + trow * 64 + coff);
        float4 p1 = *(const float4*)(pos_emb + trow * 64 + coff + 4);
        union { u16 h[8]; bf16x8 v; } cv;
        cv.h[0] = f2bf(bf2f((u16)fv[0]) + p0.x); cv.h[1] = f2bf(bf2f((u16)fv[1]) + p0.y);
        cv.h[2] = f2bf(bf2f((u16)fv[2]) + p0.z); cv.h[3] = f2bf(bf2f((u16)fv[3]) + p0.w);
        cv.h[4] = f2bf(bf2f((u16)fv[4]) + p1.x); cv.h[5] = f2bf(bf2f((u16)fv[5]) + p1.y);
        cv.h[6] = f2bf(bf2f((u16)fv[6]) + p1.z); cv.h[7] = f2bf(bf2f((u16)fv[7]) + p1.w);
        bf16x8 a = cv.v;
        const u16* bb = qkv_pad + ks * 32 + quad * 8;
        #pragma unroll
        for (int cf = 0; cf < 12; ++cf) {
            bf16x8 b = *(const bf16x8*)(bb + (cf * 16 + col) * 72);
            acc[cf] = __builtin_amdgcn_mfma_f32_16x16x32_bf16(a, b, acc[cf], 0, 0, 0);
        }
    }
    #pragma unroll
    for (int cf = 0; cf < 12; ++cf) {
        int g = cf * 16 + col;
        #pragma unroll
        for (int reg = 0; reg < 4; ++reg) {
            int rl = wv * 16 + quad * 4 + reg;
            qkv_s[rl * 200 + g] = acc[cf][reg];
        }
    }
    __syncthreads();

    int nl = wv * 4 + (lane >> 4);
    int sub = lane & 15;
    int h = sub >> 2, tq = sub & 3;
    const float* qrow = qkv_s + (nl * 4 + tq) * 200 + h * 16;

    float s[4];
    #pragma unroll
    for (int tk = 0; tk < 4; ++tk) {
        const float* krow = qkv_s + (nl * 4 + tk) * 200 + 64 + h * 16;
        float d = 0.f;
        #pragma unroll
        for (int j = 0; j < 16; ++j) d += qrow[j] * krow[j];
        s[tk] = (tk > tq) ? -4294967295.0f : d * 0.5f;
    }
    float mx = fmaxf(fmaxf(s[0], s[1]), fmaxf(s[2], s[3]));
    float a0 = __expf(s[0]-mx), a1 = __expf(s[1]-mx), a2 = __expf(s[2]-mx), a3 = __expf(s[3]-mx);
    float inv = 1.f / (a0 + a1 + a2 + a3);
    a0 *= inv; a1 *= inv; a2 *= inv; a3 *= inv;

    int n = blockIdx.x * 16 + nl;
    const float* v0 = qkv_s + (nl * 4 + 0) * 200 + 128 + h * 16;
    const float* v1 = v0 + 200, *v2 = v0 + 400, *v3 = v0 + 600;
    #pragma unroll
    for (int cc4 = 0; cc4 < 4; ++cc4) {
        float4 o;
        o.x = a0*v0[cc4*4+0] + a1*v1[cc4*4+0] + a2*v2[cc4*4+0] + a3*v3[cc4*4+0];
        o.y = a0*v0[cc4*4+1] + a1*v1[cc4*4+1] + a2*v2[cc4*4+1] + a3*v3[cc4*4+1];
        o.z = a0*v0[cc4*4+2] + a1*v1[cc4*4+2] + a2*v2[cc4*4+2] + a3*v3[cc4*4+2];
        o.w = a0*v0[cc4*4+3] + a1*v1[cc4*4+3] + a2*v2[cc4*4+3] + a3*v3[cc4*4+3];
        *(float4*)(out + (size_t)n * 256 + tq * 64 + h * 16 + cc4 * 4) = o;
    }
}

// ---------------- launcher ----------------
extern "C" void kernel_launch(void* const* d_in, const int* in_sizes, int n_in,
                              void* d_out, int out_size, void* d_ws, size_t ws_size,
                              hipStream_t stream) {
    const float* x     = (const float*)d_in[0];
    const int* ei      = (const int*)d_in[1];
    const float* Wsrc  = (const float*)d_in[2];
    const float* Wdst  = (const float*)d_in[3];
    const float* att_src = (const float*)d_in[4];
    const float* att_dst = (const float*)d_in[5];
    const float* raW1  = (const float*)d_in[6];
    const float* rab1  = (const float*)d_in[7];
    const float* raW2  = (const float*)d_in[8];
    const float* Wih   = (const float*)d_in[9];
    const float* Whh   = (const float*)d_in[10];
    const float* bih   = (const float*)d_in[11];
    const float* bhh   = (const float*)d_in[12];
    const float* pos   = (const float*)d_in[13];
    const float* Wq    = (const float*)d_in[14];
    const float* Wk    = (const float*)d_in[15];
    const float* Wv    = (const float*)d_in[16];
    float* out = (float*)d_out;

    char* w = (char*)d_ws;
    size_t off = 0;
    auto alloc = [&](size_t bytes) -> char* {
        char* pp = w + off; off += (bytes + 255) & ~(size_t)255; return pp;
    };
    // ---- long-lived ----
    u16*   intra     = (u16*)  alloc((size_t)T_ * N_ * R_ * 64 * 2);  // 20.48 MB
    u16*   x_bf      = (u16*)  alloc((size_t)T_ * N_ * 64 * 2);       // 10.24 MB
    float* ssum      = (float*)alloc(256);
    float* wdall     = (float*)alloc(1024 * 4);
    float* biasv     = (float*)alloc(256 * 4);
    u16*   raW1_pad  = (u16*)  alloc(BPAD * 2);
    u16*   Wc_pad    = (u16*)  alloc(2 * BPAD * 2);
    u16*   qkv_pad   = (u16*)  alloc(192 * 72 * 2);
    u16*   postB_pad = (u16*)  alloc(2 * 4 * 4608 * 2);
    int*   chunktot  = (int*)  alloc(P_ * NB_ * 4);
    int*   chunkbase = (int*)  alloc(P_ * NB_ * 4);
    // ---- union region ----
    char*  ubase   = alloc(0);
    size_t uoff = 0;
    auto ualloc = [&](size_t bytes) -> char* {
        char* pp = ubase + uoff; uoff += (bytes + 255) & ~(size_t)255; return pp;
    };
    int*   offsets = (int*)  ualloc((size_t)P_ * (N_ + 1) * 4);
    u16*   csr     = (u16*)  ualloc((size_t)P_ * E_ * 2);
    float* als_all = (float*)ualloc((size_t)P_ * N_ * 4 * 4);
    float* ald_all = (float*)ualloc((size_t)P_ * N_ * 4 * 4);
    u16*   partial = (u16*)  ualloc((size_t)P_ * NB_ * N_ * 2);
    u16*   xagg4   = (u16*)  ualloc((size_t)P_ * N_ * 256 * 2);   // 81.92 MB (all t,r)
    u16*   rank    = (u16*)  xagg4;   // overlay: rank dead before k_agg
    // phase 2 overlay (phase-1 sub-buffers dead after k_post)
    u16*   feats   = (u16*)  ubase;   // 10.24 MB
    (void)ws_size; (void)in_sizes; (void)n_in; (void)out_size;

    k_prep<<<72, 256, 0, stream>>>(Wdst, att_dst, Wih, Whh, bih, bhh, Wsrc, att_src, raW1,
                                   Wq, Wk, Wv, wdall, biasv, raW1_pad, Wc_pad, qkv_pad, postB_pad);
    k_hist<<<dim3(NB_, 8), 256, 0, stream>>>(ei, rank, partial);
    k_scan1<<<dim3(NB_, 8), 256, 0, stream>>>(partial, offsets, chunktot);
    k_scan2<<<1, 64, 0, stream>>>(chunktot, chunkbase);
    k_scan3<<<dim3(79, 8), 256, 0, stream>>>(offsets, chunkbase);
    k_scatter<<<dim3(1250, 8), 256, 0, stream>>>(ei, offsets, rank, partial, csr);
    k_fold<<<dim3(313, 4), 256, 0, stream>>>(x, wdall, als_all, ald_all, x_bf);
    k_agg<<<dim3(5000, 2, 4), 256, 0, stream>>>(offsets, csr, als_all, ald_all, x_bf, xagg4);
    k_post<<<dim3(313, 2, 4), 256, 0, stream>>>(xagg4, postB_pad, intra);
    hipMemsetAsync(ssum, 0, 32, stream);
    k_relagg<<<2500, 256, 0, stream>>>(intra, raW1_pad, rab1, raW2, ssum);
    k_lstm<<<313, 256, 0, stream>>>(intra, ssum, Wc_pad, biasv, feats);
    k_attn<<<1250, 256, 0, stream>>>(feats, pos, qkv_pad, out);
}